// Round 4
// baseline (583.810 us; speedup 1.0000x reference)
//
#include <hip/hip_runtime.h>
#include <math.h>

__device__ __forceinline__ float silu(float x) { return x / (1.0f + __expf(-x)); }

// ---------------- Kernel 1: per-node precompute ----------------
__global__ __launch_bounds__(320) void node_pre_kernel(
    const float* __restrict__ nf, const float* __restrict__ na,
    const float* __restrict__ w0, const float* __restrict__ w1,
    const float* __restrict__ scw0, const float* __restrict__ scw1,
    float* __restrict__ y, float* __restrict__ sc)
{
  __shared__ float snf[128];
  __shared__ float sna[4];
  const int n = blockIdx.x;
  const int t = threadIdx.x;
  if (t < 128) snf[t] = nf[n * 128 + t];
  if (t >= 128 && t < 132) sna[t - 128] = na[n * 4 + (t - 128)];
  __syncthreads();
  const float inv_sqrt32 = 0.17677669529663687f;
  const float sc_norm    = 0.08838834764831843f;  // 1/sqrt(32*4)
  if (t < 32) {
    const int w = t;
    float acc = 0.f;
    for (int u = 0; u < 32; ++u) acc += snf[u] * w0[u * 32 + w];
    y[n * 128 + w] = acc * inv_sqrt32;
  } else if (t < 128) {
    const int q = t - 32, w = q / 3, i = q - w * 3;
    float acc = 0.f;
    for (int u = 0; u < 32; ++u) acc += snf[32 + u * 3 + i] * w1[u * 32 + w];
    y[n * 128 + 32 + w * 3 + i] = acc * inv_sqrt32;
  } else if (t < 192) {
    const int w = t - 128;
    float acc = 0.f;
    for (int k = 0; k < 128; ++k) acc += snf[k >> 2] * sna[k & 3] * scw0[k * 64 + w];
    sc[n * 160 + w] = acc * sc_norm;
  } else if (t < 288) {
    const int q = t - 192, w = q / 3, i = q - w * 3;
    float acc = 0.f;
    for (int k = 0; k < 128; ++k) acc += snf[32 + (k >> 2) * 3 + i] * sna[k & 3] * scw1[k * 32 + w];
    sc[n * 160 + 64 + w * 3 + i] = acc * sc_norm;
  }
}

// ---------------- CSR build (runs BEFORE the MLP now) ----------------
__global__ __launch_bounds__(256) void hist_kernel(const int* __restrict__ eidx,
                                                   int* __restrict__ counts, int E)
{
  const int e = blockIdx.x * 256 + threadIdx.x;
  if (e < E) atomicAdd(&counts[eidx[E + e]], 1);
}

__global__ __launch_bounds__(1024) void scan_kernel(const int* __restrict__ counts,
                                                    int* __restrict__ offsets,
                                                    int* __restrict__ cursor, int N)
{
  __shared__ int part[1024];
  const int t = threadIdx.x;
  const int per = (N + 1023) / 1024;
  const int base = t * per;
  int s = 0;
  for (int k = 0; k < per; ++k) { int idx = base + k; if (idx < N) s += counts[idx]; }
  part[t] = s;
  __syncthreads();
  for (int off = 1; off < 1024; off <<= 1) {
    int v = part[t];
    if (t >= off) v += part[t - off];
    __syncthreads();
    part[t] = v;
    __syncthreads();
  }
  int run = (t == 0) ? 0 : part[t - 1];
  for (int k = 0; k < per; ++k) {
    int idx = base + k;
    if (idx < N) { offsets[idx] = run; cursor[idx] = run; run += counts[idx]; }
  }
  if (t == 1023) offsets[N] = run;
}

__global__ __launch_bounds__(256) void scatter_kernel(const int* __restrict__ eidx,
                                                      int* __restrict__ cursor,
                                                      int* __restrict__ elist, int E)
{
  const int e = blockIdx.x * 256 + threadIdx.x;
  if (e >= E) return;
  const int dst = eidx[E + e];
  const int slot = atomicAdd(&cursor[dst], 1);
  elist[slot] = e;
}

// ---------------- Kernel 2a: layers 1+2, SLOT-major -> h2 into wbuf[slot][0:64]
__global__ __launch_bounds__(256, 4) void edge_h2_kernel(
    const float* __restrict__ eemb, const float* __restrict__ fw1,
    const float* __restrict__ fw2, const int* __restrict__ elist,
    float* __restrict__ wbuf, int E)
{
  __shared__ __align__(16) float w1L[512];    // [k<64][r<8] (transposed)
  __shared__ __align__(16) float w2L[4096];   // [k<64][j<64] (as-is)
  const int t = threadIdx.x;
  for (int x = t; x < 512; x += 256)  w1L[x] = fw1[(x & 7) * 64 + (x >> 3)];
  for (int x = t; x < 4096; x += 256) w2L[x] = fw2[x];
  __syncthreads();

  const int s = blockIdx.x * 256 + t;
  if (s >= E) return;
  const int e = elist[s];
  const float4 emb0 = *(const float4*)(eemb + (size_t)e * 8);
  const float4 emb1 = *(const float4*)(eemb + (size_t)e * 8 + 4);
  const float inv_sqrt8 = 0.35355339059327373f;

  float acc[64];
#pragma unroll
  for (int j = 0; j < 64; ++j) acc[j] = 0.f;

  for (int k = 0; k < 64; ++k) {
    const float4* wp = (const float4*)(w1L + k * 8);
    const float4 wa = wp[0], wb = wp[1];
    float a = emb0.x * wa.x + emb0.y * wa.y + emb0.z * wa.z + emb0.w * wa.w
            + emb1.x * wb.x + emb1.y * wb.y + emb1.z * wb.z + emb1.w * wb.w;
    const float h1k = silu(a * inv_sqrt8);
    const float4* row = (const float4*)(w2L + k * 64);
#pragma unroll
    for (int jj = 0; jj < 16; ++jj) {
      const float4 w = row[jj];
      acc[jj * 4 + 0] += h1k * w.x;
      acc[jj * 4 + 1] += h1k * w.y;
      acc[jj * 4 + 2] += h1k * w.z;
      acc[jj * 4 + 3] += h1k * w.w;
    }
  }
  float* out = wbuf + (size_t)s * 128;
#pragma unroll
  for (int j = 0; j < 64; j += 4) {
    float4 v;
    v.x = silu(acc[j + 0] * 0.125f);
    v.y = silu(acc[j + 1] * 0.125f);
    v.z = silu(acc[j + 2] * 0.125f);
    v.w = silu(acc[j + 3] * 0.125f);
    *(float4*)(out + j) = v;
  }
}

// ---------------- Kernel 2b: layer 3, row-local (order-agnostic) ----------
__global__ __launch_bounds__(256, 3) void edge_w3_kernel(
    const float* __restrict__ fw3, float* __restrict__ wbuf, int E)
{
  __shared__ __align__(16) float w3L[8192];   // [k<64][c<128] (as-is)
  const int t = threadIdx.x;
  for (int x = t; x < 8192; x += 256) w3L[x] = fw3[x];
  __syncthreads();

  const int s = blockIdx.x * 256 + t;
  if (s >= E) return;
  float* row = wbuf + (size_t)s * 128;

  float h2[64];
#pragma unroll
  for (int j = 0; j < 64; j += 4) {
    const float4 v = *(const float4*)(row + j);
    h2[j] = v.x; h2[j + 1] = v.y; h2[j + 2] = v.z; h2[j + 3] = v.w;
  }

  for (int c0 = 0; c0 < 128; c0 += 32) {
    float aw[32];
#pragma unroll
    for (int c = 0; c < 32; ++c) aw[c] = 0.f;
#pragma unroll
    for (int k = 0; k < 64; ++k) {          // fully unrolled: h2[k] static
      const float4* wr = (const float4*)(w3L + k * 128 + c0);
#pragma unroll
      for (int cc = 0; cc < 8; ++cc) {
        const float4 w = wr[cc];
        aw[cc * 4 + 0] += h2[k] * w.x;
        aw[cc * 4 + 1] += h2[k] * w.y;
        aw[cc * 4 + 2] += h2[k] * w.z;
        aw[cc * 4 + 3] += h2[k] * w.w;
      }
    }
#pragma unroll
    for (int c = 0; c < 32; c += 4) {
      float4 v;
      v.x = aw[c] * 0.125f; v.y = aw[c + 1] * 0.125f;
      v.z = aw[c + 2] * 0.125f; v.w = aw[c + 3] * 0.125f;
      *(float4*)(row + c0 + c) = v;
    }
  }
}

// ---------------- Kernel 3: gather (sequential wbuf) + lin2 + gate + residual
__global__ __launch_bounds__(256) void gather_out_kernel(
    const float* __restrict__ nf, const float* __restrict__ wbuf,
    const float* __restrict__ y, const float* __restrict__ sc,
    const float* __restrict__ l2w0, const float* __restrict__ l2w1,
    const int* __restrict__ offsets, const int* __restrict__ elist,
    const int* __restrict__ eidx, const float* __restrict__ eattr,
    const int* __restrict__ avgp, float* __restrict__ out, int E)
{
  __shared__ float sm[256];
  __shared__ float so0[64];
  __shared__ float so1[96];
  const int n = blockIdx.x, t = threadIdx.x;

  int wi, yi0, yi1, yi2, selA;  // selA: 0=e0,1=e1x,2=e1y,3=e1z
  bool is1 = false;
  if (t < 32) {            // o_s0[u]
    wi = t; yi0 = yi1 = yi2 = t; selA = 0;
  } else if (t < 64) {     // o_s1[u]
    const int u = t - 32;
    wi = 96 + u; yi0 = 32 + 3 * u; yi1 = yi0 + 1; yi2 = yi0 + 2; selA = 1; is1 = true;
  } else if (t < 160) {    // o_v0[u][i]
    const int q = t - 64, u = q / 3, i = q - u * 3;
    wi = 32 + u; yi0 = yi1 = yi2 = u; selA = 1 + i;
  } else {                 // o_v1[u][i]
    const int q = t - 160, u = q / 3, i = q - u * 3;
    wi = 64 + u; yi0 = yi1 = yi2 = 32 + 3 * u + i; selA = 0;
  }

  const int beg = offsets[n], end = offsets[n + 1];
  const int deg = end - beg;
  float accv = 0.f;

  for (int j0 = 0; j0 < deg; j0 += 4) {
    int eidq[4];
#pragma unroll
    for (int q = 0; q < 4; ++q) {
      const int j = j0 + q;
      eidq[q] = (j < deg) ? elist[beg + j] : -1;
    }
    int srcq[4]; float4 eaq[4]; float wq[4];
#pragma unroll
    for (int q = 0; q < 4; ++q) {
      if (eidq[q] >= 0) {
        srcq[q] = eidx[eidq[q]];
        eaq[q]  = *(const float4*)(eattr + (size_t)eidq[q] * 4);
        wq[q]   = wbuf[(size_t)(beg + j0 + q) * 128 + wi];
      } else {
        srcq[q] = 0; eaq[q] = make_float4(0.f, 0.f, 0.f, 0.f); wq[q] = 0.f;
      }
    }
#pragma unroll
    for (int q = 0; q < 4; ++q) {
      const float* yr = y + (size_t)srcq[q] * 128;
      const float A = (selA == 0) ? eaq[q].x : (selA == 1) ? eaq[q].y
                    : (selA == 2) ? eaq[q].z : eaq[q].w;
      if (is1) {
        accv += wq[q] * (A * yr[yi0] + eaq[q].z * yr[yi1] + eaq[q].w * yr[yi2]);
      } else {
        accv += wq[q] * (A * yr[yi0]);
      }
    }
  }
  const float inv_sqrt3 = 0.5773502691896258f;
  if (is1) accv *= inv_sqrt3;
  sm[t] = accv * rsqrtf((float)(*avgp));
  __syncthreads();

  if (t < 64) {
    float acc = 0.f;
    for (int u = 0; u < 64; ++u) acc += sm[u] * l2w0[u * 64 + t];
    so0[t] = acc * 0.125f + sc[n * 160 + t];
  } else if (t < 160) {
    const int q = t - 64, w = q / 3, i = q - w * 3;
    float acc = 0.f;
    for (int u = 0; u < 64; ++u) acc += sm[64 + u * 3 + i] * l2w1[u * 32 + w];
    so1[w * 3 + i] = acc * 0.125f + sc[n * 160 + 64 + w * 3 + i];
  }
  __syncthreads();
  if (t < 32) {
    out[n * 128 + t] = nf[n * 128 + t] + silu(so0[t]);
  } else if (t < 128) {
    const int q = t - 32, w = q / 3, i = q - w * 3;
    out[n * 128 + t] = nf[n * 128 + t] + silu(so0[32 + w]) * so1[w * 3 + i];
  }
}

extern "C" void kernel_launch(void* const* d_in, const int* in_sizes, int n_in,
                              void* d_out, int out_size, void* d_ws, size_t ws_size,
                              hipStream_t stream)
{
  const float* nf    = (const float*)d_in[0];
  const float* na    = (const float*)d_in[1];
  const float* eattr = (const float*)d_in[2];
  const float* eemb  = (const float*)d_in[3];
  const float* l1w0  = (const float*)d_in[4];
  const float* l1w1  = (const float*)d_in[5];
  const float* fw1   = (const float*)d_in[6];
  const float* fw2   = (const float*)d_in[7];
  const float* fw3   = (const float*)d_in[8];
  const float* l2w0  = (const float*)d_in[9];
  const float* l2w1  = (const float*)d_in[10];
  const float* scw0  = (const float*)d_in[11];
  const float* scw1  = (const float*)d_in[12];
  const int*   eidx  = (const int*)d_in[13];
  const int*   avgp  = (const int*)d_in[14];

  const int N = in_sizes[0] / 128;
  const int E = in_sizes[2] / 4;

  // Same byte layout as R3 (known to fit in ws_size).
  float* y       = (float*)d_ws;                    // N*128
  float* sc      = y + (size_t)N * 128;             // N*160
  float* wbuf    = sc + (size_t)N * 160;            // E*128  (SORTED by dst slot)
  int*   counts  = (int*)(wbuf + (size_t)E * 128);  // N
  int*   offsets = counts + N;                      // N+1
  int*   cursor  = offsets + N + 1;                 // N
  int*   elist   = cursor + N;                      // E (slot -> eid)

  hipMemsetAsync(counts, 0, (size_t)N * sizeof(int), stream);
  node_pre_kernel<<<N, 320, 0, stream>>>(nf, na, l1w0, l1w1, scw0, scw1, y, sc);
  hist_kernel<<<(E + 255) / 256, 256, 0, stream>>>(eidx, counts, E);
  scan_kernel<<<1, 1024, 0, stream>>>(counts, offsets, cursor, N);
  scatter_kernel<<<(E + 255) / 256, 256, 0, stream>>>(eidx, cursor, elist, E);
  edge_h2_kernel<<<(E + 255) / 256, 256, 0, stream>>>(eemb, fw1, fw2, elist, wbuf, E);
  edge_w3_kernel<<<(E + 255) / 256, 256, 0, stream>>>(fw3, wbuf, E);
  gather_out_kernel<<<N, 256, 0, stream>>>(nf, wbuf, y, sc, l2w0, l2w1,
                                           offsets, elist, eidx, eattr, avgp,
                                           (float*)d_out, E);
}